// Round 1
// baseline (686.433 us; speedup 1.0000x reference)
//
#include <hip/hip_runtime.h>
#include <hip/hip_bf16.h>
#include <math.h>

#define N_ROI 8192
#define C_IN  1024
#define HIDD  256
#define FGD   64
#define CLSD  128
#define INV_TAU 5.0f

// ---------------- prep ----------------
__global__ void prep_zero_kernel(float* accum, int* cnt) {
  int t = threadIdx.x;
  if (t < 8) accum[t] = 0.f;
  if (t < 24) cnt[t] = 0;
}

__global__ void prep_stats_kernel(const int* __restrict__ labels,
                                  float* __restrict__ Sfg, float* __restrict__ Pfg,
                                  float* __restrict__ Scls, float* __restrict__ SPc,
                                  int* __restrict__ cnt) {
  int i = blockIdx.x * blockDim.x + threadIdx.x;
  if (i >= N_ROI) return;
  Sfg[i] = 0.f; Pfg[i] = 0.f; Scls[i] = 0.f; SPc[i] = 0.f;
  int l = labels[i];
  int b = l + 1; if (b < 0) b = 0; if (b > 21) b = 21;
  atomicAdd(&cnt[b], 1);
}

// ---------------- GEMM: C[m][n] = act(bias[n] + sum_k A[m][k]*B[n][k]) ----------------
// A: MxK row-major, B: NxK row-major (NT). 64x64 tile, 4x4 per thread, BK=16.
__global__ __launch_bounds__(256) void gemm_nt_kernel(
    const float* __restrict__ A, const float* __restrict__ B,
    const float* __restrict__ bias, float* __restrict__ Cd,
    int M, int N, int K, int relu) {
  __shared__ float At[16][68];
  __shared__ float Bt[16][68];
  int tid = threadIdx.x;
  int tx = tid & 15, ty = tid >> 4;
  int m0 = blockIdx.x << 6, n0 = blockIdx.y << 6;
  int lr = tid >> 2;          // 0..63
  int lc = (tid & 3) << 2;    // 0,4,8,12
  const float* Ap = A + (size_t)(m0 + lr) * K + lc;
  const float* Bp = B + (size_t)(n0 + lr) * K + lc;
  float acc[4][4] = {};
  for (int k0 = 0; k0 < K; k0 += 16) {
    float4 av = *(const float4*)(Ap + k0);
    float4 bv = *(const float4*)(Bp + k0);
    __syncthreads();
    At[lc+0][lr] = av.x; At[lc+1][lr] = av.y; At[lc+2][lr] = av.z; At[lc+3][lr] = av.w;
    Bt[lc+0][lr] = bv.x; Bt[lc+1][lr] = bv.y; Bt[lc+2][lr] = bv.z; Bt[lc+3][lr] = bv.w;
    __syncthreads();
    #pragma unroll
    for (int kk = 0; kk < 16; ++kk) {
      float a[4], b[4];
      *(float4*)a = *(const float4*)&At[kk][ty << 2];
      *(float4*)b = *(const float4*)&Bt[kk][tx << 2];
      #pragma unroll
      for (int ii = 0; ii < 4; ++ii)
        #pragma unroll
        for (int jj = 0; jj < 4; ++jj)
          acc[ii][jj] += a[ii] * b[jj];
    }
  }
  float bb[4];
  *(float4*)bb = *(const float4*)&bias[n0 + (tx << 2)];
  #pragma unroll
  for (int ii = 0; ii < 4; ++ii) {
    float o[4];
    #pragma unroll
    for (int jj = 0; jj < 4; ++jj) {
      float v = acc[ii][jj] + bb[jj];
      o[jj] = relu ? fmaxf(v, 0.f) : v;
    }
    *(float4*)&Cd[(size_t)(m0 + (ty<<2) + ii) * N + n0 + (tx<<2)] = *(float4*)o;
  }
}

// ---------------- row L2 normalize (z / max(||z||, 1e-8)) ----------------
__global__ void normalize_kernel(float* __restrict__ Z, int D) {
  int i = blockIdx.x;
  int t = threadIdx.x;         // blockDim == D (64 or 128)
  size_t idx = (size_t)i * D + t;
  float v = Z[idx];
  float s = v * v;
  #pragma unroll
  for (int m = 1; m < 64; m <<= 1) s += __shfl_xor(s, m);
  __shared__ float red[2];
  if (blockDim.x > 64) {
    if ((t & 63) == 0) red[t >> 6] = s;
    __syncthreads();
    s = red[0] + red[1];
  }
  float scale = 1.f / fmaxf(sqrtf(s), 1e-8f);
  Z[idx] = v * scale;
}

// ---------------- fused Gram-row-reduction loss kernel ----------------
// MODE 0 (fg):  Sg[i] += sum_{j!=i} e^{s_ij};  Pg[i] += sum_{j!=i, lbl_j>0} e^{s_ij}
// MODE 1 (cls): Sg[i] += sum_{j!=i, lbl_j!=-1} e^{s_ij};  Pg[i] += sum_{pos} s_ij
template<int D, int MODE>
__global__ __launch_bounds__(256) void loss_main_kernel(
    const float* __restrict__ Z, const int* __restrict__ labels,
    float* __restrict__ Sg, float* __restrict__ Pg) {
  __shared__ float Zti[D][68];    // transposed i-tile: [d][i_local]
  __shared__ float Ztj[64][68];   // transposed j-chunk: [d_local][j_local]
  __shared__ int   lblj[64];
  __shared__ float redS[64];
  __shared__ float redP[64];
  int tid = threadIdx.x;
  int tx = tid & 15, ty = tid >> 4;
  int i0 = blockIdx.x << 6;
  // load Zti (64 rows x D) transposed
  for (int f = tid; f < 16 * D; f += 256) {     // 64*D/4 float4s
    int r  = f / (D / 4);
    int c4 = (f % (D / 4)) << 2;
    float4 v = *(const float4*)&Z[(size_t)(i0 + r) * D + c4];
    Zti[c4+0][r] = v.x; Zti[c4+1][r] = v.y; Zti[c4+2][r] = v.z; Zti[c4+3][r] = v.w;
  }
  int lbl_i[4];
  #pragma unroll
  for (int ii = 0; ii < 4; ++ii)
    lbl_i[ii] = (MODE == 1) ? labels[i0 + (ty<<2) + ii] : 0;
  float Ssum[4] = {}, Psum[4] = {};
  for (int jt = blockIdx.y; jt < N_ROI/64; jt += gridDim.y) {
    int j0 = jt << 6;
    float dot[4][4] = {};
    #pragma unroll
    for (int c = 0; c < D/64; ++c) {
      __syncthreads();  // previous chunk/tile fully consumed before overwrite
      #pragma unroll
      for (int q = 0; q < 4; ++q) {
        int f = tid + (q << 8);
        int row = f >> 4;
        int c4 = (f & 15) << 2;
        float4 v = *(const float4*)&Z[(size_t)(j0 + row) * D + (c << 6) + c4];
        Ztj[c4+0][row] = v.x; Ztj[c4+1][row] = v.y; Ztj[c4+2][row] = v.z; Ztj[c4+3][row] = v.w;
      }
      if (c == 0 && tid < 64) lblj[tid] = labels[j0 + tid];
      __syncthreads();
      #pragma unroll 8
      for (int d = 0; d < 64; ++d) {
        float a[4], b[4];
        *(float4*)a = *(const float4*)&Zti[(c<<6)+d][ty << 2];
        *(float4*)b = *(const float4*)&Ztj[d][tx << 2];
        #pragma unroll
        for (int ii = 0; ii < 4; ++ii)
          #pragma unroll
          for (int jj = 0; jj < 4; ++jj)
            dot[ii][jj] += a[ii] * b[jj];
      }
    }
    #pragma unroll
    for (int jj = 0; jj < 4; ++jj) {
      int lj = lblj[(tx<<2) + jj];
      int gj = j0 + (tx<<2) + jj;
      #pragma unroll
      for (int ii = 0; ii < 4; ++ii) {
        int gi = i0 + (ty<<2) + ii;
        float s = dot[ii][jj] * INV_TAU;
        float e = __expf(s);
        float m = (gi == gj) ? 0.f : 1.f;
        if (MODE == 0) {
          Ssum[ii] += m * e;
          Psum[ii] += (lj > 0) ? m * e : 0.f;
        } else {
          Ssum[ii] += (lj != -1) ? m * e : 0.f;
          Psum[ii] += (lj > 0 && lj == lbl_i[ii]) ? m * s : 0.f;
        }
      }
    }
  }
  // reduce partial sums across tx groups, then one global atomic per row
  __syncthreads();
  if (tid < 64) { redS[tid] = 0.f; redP[tid] = 0.f; }
  __syncthreads();
  #pragma unroll
  for (int ii = 0; ii < 4; ++ii) {
    atomicAdd(&redS[(ty<<2) + ii], Ssum[ii]);
    atomicAdd(&redP[(ty<<2) + ii], Psum[ii]);
  }
  __syncthreads();
  if (tid < 64) {
    atomicAdd(&Sg[i0 + tid], redS[tid]);
    atomicAdd(&Pg[i0 + tid], redP[tid]);
  }
}

// ---------------- per-row losses + weighted reduction ----------------
__global__ __launch_bounds__(256) void finalize_kernel(
    const float* __restrict__ Sfg, const float* __restrict__ Pfg,
    const float* __restrict__ Scls, const float* __restrict__ SPc,
    const int* __restrict__ labels, const float* __restrict__ ious,
    const int* __restrict__ cnt, float* __restrict__ accum) {
  int i = blockIdx.x * 256 + threadIdx.x;
  int l = labels[i];
  float iv = ious[i];
  float w = (iv > 0.5f) ? iv : 0.f;
  int cntP = 0;
  #pragma unroll
  for (int b = 2; b <= 21; ++b) cntP += cnt[b];   // labels 1..20
  int cntNI = N_ROI - cnt[0];
  bool Pi = (l > 0);
  float numF = 0.f, denF = 0.f, numC = 0.f, denC = 0.f;
  int nposF = cntP - (Pi ? 1 : 0);
  if (Pi && nposF > 0) {
    // -log((P+eps)/(S+eps)) == log((S+eps)/(P+eps))
    float lossF = logf((Sfg[i] + 1e-8f) / (Pfg[i] + 1e-8f));
    numF = lossF * w; denF = w;
  }
  int nposC = Pi ? (cnt[l + 1] - 1) : 0;
  bool anyv = (cntNI - ((l != -1) ? 1 : 0)) > 0;
  if (Pi && nposC > 0 && anyv) {
    float lse = logf(Scls[i]);    // sims bounded in [-5,5]; no max-sub needed
    float lossC = -(SPc[i] - (float)nposC * lse) / fmaxf((float)nposC, 1.f);
    numC = lossC * w; denC = w;
  }
  float v0 = numF, v1 = denF, v2 = numC, v3 = denC;
  #pragma unroll
  for (int m = 1; m < 64; m <<= 1) {
    v0 += __shfl_xor(v0, m); v1 += __shfl_xor(v1, m);
    v2 += __shfl_xor(v2, m); v3 += __shfl_xor(v3, m);
  }
  __shared__ float red[4][4];
  int lane = threadIdx.x & 63, wid = threadIdx.x >> 6;
  if (lane == 0) { red[wid][0]=v0; red[wid][1]=v1; red[wid][2]=v2; red[wid][3]=v3; }
  __syncthreads();
  if (threadIdx.x == 0) {
    float s0=0,s1=0,s2=0,s3=0;
    for (int wv = 0; wv < 4; ++wv) { s0+=red[wv][0]; s1+=red[wv][1]; s2+=red[wv][2]; s3+=red[wv][3]; }
    atomicAdd(&accum[0], s0); atomicAdd(&accum[1], s1);
    atomicAdd(&accum[2], s2); atomicAdd(&accum[3], s3);
  }
}

__global__ void write_out_kernel(const float* __restrict__ accum, float* __restrict__ out) {
  out[0] = accum[0] / (accum[1] + 1e-8f);
  out[1] = accum[2] / (accum[3] + 1e-12f);
}

extern "C" void kernel_launch(void* const* d_in, const int* in_sizes, int n_in,
                              void* d_out, int out_size, void* d_ws, size_t ws_size,
                              hipStream_t stream) {
  const float* X    = (const float*)d_in[0];
  const int*  labels= (const int*)d_in[1];
  const float* ious = (const float*)d_in[2];
  const float* w1f  = (const float*)d_in[3];
  const float* b1f  = (const float*)d_in[4];
  const float* w2f  = (const float*)d_in[5];
  const float* b2f  = (const float*)d_in[6];
  const float* w1c  = (const float*)d_in[7];
  const float* b1c  = (const float*)d_in[8];
  const float* w2c  = (const float*)d_in[9];
  const float* b2c  = (const float*)d_in[10];
  float* out = (float*)d_out;

  float* ws   = (float*)d_ws;
  float* H    = ws;                                // 8192*256
  float* Zf   = H  + (size_t)N_ROI * HIDD;         // 8192*64
  float* Zc   = Zf + (size_t)N_ROI * FGD;          // 8192*128
  float* Sfg  = Zc + (size_t)N_ROI * CLSD;
  float* Pfg  = Sfg + N_ROI;
  float* Scls = Pfg + N_ROI;
  float* SPc  = Scls + N_ROI;
  float* accum= SPc + N_ROI;                       // 8 floats
  int*   cnt  = (int*)(accum + 8);                 // 24 ints

  prep_zero_kernel<<<1, 64, 0, stream>>>(accum, cnt);
  prep_stats_kernel<<<N_ROI/256, 256, 0, stream>>>(labels, Sfg, Pfg, Scls, SPc, cnt);

  // fg head: H = relu(X@W1f^T + b1f); Zf = H@W2f^T + b2f; normalize
  gemm_nt_kernel<<<dim3(N_ROI/64, HIDD/64), 256, 0, stream>>>(X, w1f, b1f, H, N_ROI, HIDD, C_IN, 1);
  gemm_nt_kernel<<<dim3(N_ROI/64, FGD/64),  256, 0, stream>>>(H, w2f, b2f, Zf, N_ROI, FGD, HIDD, 0);
  normalize_kernel<<<N_ROI, FGD, 0, stream>>>(Zf, FGD);
  // cls head (H reused)
  gemm_nt_kernel<<<dim3(N_ROI/64, HIDD/64), 256, 0, stream>>>(X, w1c, b1c, H, N_ROI, HIDD, C_IN, 1);
  gemm_nt_kernel<<<dim3(N_ROI/64, CLSD/64), 256, 0, stream>>>(H, w2c, b2c, Zc, N_ROI, CLSD, HIDD, 0);
  normalize_kernel<<<N_ROI, CLSD, 0, stream>>>(Zc, CLSD);

  // fused Gram-row reductions (j-split x8 for occupancy: 1024 blocks)
  loss_main_kernel<FGD, 0><<<dim3(N_ROI/64, 8), 256, 0, stream>>>(Zf, labels, Sfg, Pfg);
  loss_main_kernel<CLSD, 1><<<dim3(N_ROI/64, 8), 256, 0, stream>>>(Zc, labels, Scls, SPc);

  finalize_kernel<<<N_ROI/256, 256, 0, stream>>>(Sfg, Pfg, Scls, SPc, labels, ious, cnt, accum);
  write_out_kernel<<<1, 1, 0, stream>>>(accum, out);
}

// Round 2
// 348.901 us; speedup vs baseline: 1.9674x; 1.9674x over previous
//
#include <hip/hip_runtime.h>
#include <hip/hip_bf16.h>
#include <math.h>

#define N_ROI 8192
#define C_IN  1024
#define HIDD  256
#define FGD   64
#define CLSD  128
#define INV_TAU 5.0f

using frag_ab = __attribute__((ext_vector_type(8))) short;   // 8 bf16 = 4 VGPRs
using f32x16  = __attribute__((ext_vector_type(16))) float;

static __device__ __forceinline__ short f32_to_bf16_bits(float f) {
  unsigned u = __builtin_bit_cast(unsigned, f);
  u = (u + 0x7FFFu + ((u >> 16) & 1u)) >> 16;   // RNE (inputs finite)
  return (short)u;
}
static __device__ __forceinline__ float bf16_bits_to_f32(short b) {
  unsigned u = ((unsigned)(unsigned short)b) << 16;
  return __builtin_bit_cast(float, u);
}

// ---------------- prep ----------------
__global__ void prep_zero_kernel(float* accum, int* cnt) {
  int t = threadIdx.x;
  if (t < 8) accum[t] = 0.f;
  if (t < 24) cnt[t] = 0;
}

__global__ void prep_stats_kernel(const int* __restrict__ labels,
                                  float* __restrict__ Sfg, float* __restrict__ Pfg,
                                  float* __restrict__ Scls, float* __restrict__ SPc,
                                  float* __restrict__ pfv, float* __restrict__ nimv,
                                  float* __restrict__ ljmv, int* __restrict__ cnt) {
  int i = blockIdx.x * blockDim.x + threadIdx.x;
  if (i >= N_ROI) return;
  Sfg[i] = 0.f; Pfg[i] = 0.f; Scls[i] = 0.f; SPc[i] = 0.f;
  int l = labels[i];
  pfv[i]  = (l > 0)  ? 1.f : 0.f;
  nimv[i] = (l != -1) ? 1.f : 0.f;
  ljmv[i] = (l > 0)  ? (float)l : -7.f;   // never matches any label value
  int b = l + 1; if (b < 0) b = 0; if (b > 21) b = 21;
  atomicAdd(&cnt[b], 1);
}

// ---------------- GEMM: C[m][n] = act(bias[n] + sum_k A[m][k]*B[n][k]) ----------------
__global__ __launch_bounds__(256) void gemm_nt_kernel(
    const float* __restrict__ A, const float* __restrict__ B,
    const float* __restrict__ bias, float* __restrict__ Cd,
    int M, int N, int K, int relu) {
  __shared__ float At[16][68];
  __shared__ float Bt[16][68];
  int tid = threadIdx.x;
  int tx = tid & 15, ty = tid >> 4;
  int m0 = blockIdx.x << 6, n0 = blockIdx.y << 6;
  int lr = tid >> 2;
  int lc = (tid & 3) << 2;
  const float* Ap = A + (size_t)(m0 + lr) * K + lc;
  const float* Bp = B + (size_t)(n0 + lr) * K + lc;
  float acc[4][4] = {};
  for (int k0 = 0; k0 < K; k0 += 16) {
    float4 av = *(const float4*)(Ap + k0);
    float4 bv = *(const float4*)(Bp + k0);
    __syncthreads();
    At[lc+0][lr] = av.x; At[lc+1][lr] = av.y; At[lc+2][lr] = av.z; At[lc+3][lr] = av.w;
    Bt[lc+0][lr] = bv.x; Bt[lc+1][lr] = bv.y; Bt[lc+2][lr] = bv.z; Bt[lc+3][lr] = bv.w;
    __syncthreads();
    #pragma unroll
    for (int kk = 0; kk < 16; ++kk) {
      float a[4], b[4];
      *(float4*)a = *(const float4*)&At[kk][ty << 2];
      *(float4*)b = *(const float4*)&Bt[kk][tx << 2];
      #pragma unroll
      for (int ii = 0; ii < 4; ++ii)
        #pragma unroll
        for (int jj = 0; jj < 4; ++jj)
          acc[ii][jj] += a[ii] * b[jj];
    }
  }
  float bb[4];
  *(float4*)bb = *(const float4*)&bias[n0 + (tx << 2)];
  #pragma unroll
  for (int ii = 0; ii < 4; ++ii) {
    float o[4];
    #pragma unroll
    for (int jj = 0; jj < 4; ++jj) {
      float v = acc[ii][jj] + bb[jj];
      o[jj] = relu ? fmaxf(v, 0.f) : v;
    }
    *(float4*)&Cd[(size_t)(m0 + (ty<<2) + ii) * N + n0 + (tx<<2)] = *(float4*)o;
  }
}

// ---------------- normalize + bf16 pack into MFMA fragment order ----------------
// Zr layout: [tile=row/32][kc=col/16][lane=(colhalf<<5)|(row&31)][8 bf16]
// matches A/B frag: lane holds Z[tile*32 + lane%32][kc*16 + (lane/32)*8 + e]
__global__ void normalize_pack_kernel(const float* __restrict__ Z,
                                      short* __restrict__ Zr,
                                      float* __restrict__ tii, int D) {
  int row = blockIdx.x, t = threadIdx.x;    // blockDim == D (64 or 128)
  float v = Z[(size_t)row * D + t];
  float s = v * v;
  #pragma unroll
  for (int m = 1; m < 64; m <<= 1) s += __shfl_xor(s, m);
  __shared__ float red[2];
  __shared__ float red2[2];
  __shared__ __align__(16) short lrow[128];
  if (D > 64) {
    if ((t & 63) == 0) red[t >> 6] = s;
    __syncthreads();
    s = red[0] + red[1];
  }
  float zn = v / fmaxf(sqrtf(s), 1e-8f);
  short bits = f32_to_bf16_bits(zn);
  lrow[t] = bits;
  float zb = bf16_bits_to_f32(bits);
  float d2 = zb * zb;
  #pragma unroll
  for (int m = 1; m < 64; m <<= 1) d2 += __shfl_xor(d2, m);
  if (D > 64 && (t & 63) == 0) red2[t >> 6] = d2;
  __syncthreads();
  if (D > 64) d2 = red2[0] + red2[1];
  if (t == 0) tii[row] = d2;                 // (z_bf16 . z_bf16), fp32
  if (t < D / 8) {
    int kc = t >> 1, half = t & 1, t32 = row >> 5, r5 = row & 31;
    ((uint4*)Zr)[(size_t)(t32 * (D / 16) + kc) * 64 + half * 32 + r5] =
        ((const uint4*)lrow)[t];
  }
}

// ---------------- MFMA Gram-row-reduction loss kernel ----------------
// Full sums INCLUDING the diagonal; diag is subtracted in finalize via tii.
// MODE 0 (fg):  Sg[i] += sum_j e^{5 s_ij};           Pg[i] += sum_j pf_j e^{5 s_ij}
// MODE 1 (cls): Sg[i] += sum_j nim_j e^{5 s_ij};     Pg[i] += sum_{lbl match} 5 s_ij
template<int D, int MODE, int NJT>
__global__ __launch_bounds__(256) void loss_mfma_kernel(
    const short* __restrict__ Zr, const int* __restrict__ labels,
    const float* __restrict__ pfv, const float* __restrict__ nimv,
    const float* __restrict__ ljmv,
    float* __restrict__ Sg, float* __restrict__ Pg) {
  constexpr int KC = D / 16;
  __shared__ __align__(16) short sbuf[2][KC * 512];   // KC*64 frags of 16B
  int tid = threadIdx.x, lane = tid & 63, wv = tid >> 6;
  int itile = blockIdx.x * 4 + wv;                    // 32 i-rows per wave
  const frag_ab* Zrv = (const frag_ab*)Zr;
  frag_ab a[KC];
  #pragma unroll
  for (int kc = 0; kc < KC; ++kc) a[kc] = Zrv[(itile * KC + kc) * 64 + lane];
  float limf[16];
  if (MODE == 1) {
    #pragma unroll
    for (int r = 0; r < 16; ++r) {
      int row = (r & 3) + 8 * (r >> 2) + 4 * (lane >> 5);
      limf[r] = (float)labels[itile * 32 + row];
    }
  }
  float Ssum[16] = {}, Psum[16] = {};
  int jt0 = blockIdx.y * NJT;
  {
    const uint4* src = (const uint4*)(Zr + (size_t)jt0 * KC * 512);
    uint4* dst = (uint4*)sbuf[0];
    #pragma unroll
    for (int q = 0; q < KC * 64; q += 256) dst[q + tid] = src[q + tid];
  }
  __syncthreads();
  for (int kk = 0; kk < NJT; ++kk) {
    int jt = jt0 + kk;
    if (kk + 1 < NJT) {
      const uint4* src = (const uint4*)(Zr + (size_t)(jt + 1) * KC * 512);
      uint4* dst = (uint4*)sbuf[(kk + 1) & 1];
      #pragma unroll
      for (int q = 0; q < KC * 64; q += 256) dst[q + tid] = src[q + tid];
    }
    const frag_ab* bv = (const frag_ab*)sbuf[kk & 1];
    int j = jt * 32 + (lane & 31);
    float pf = 0.f, nim = 0.f, ljm = 0.f;
    if (MODE == 0) pf = pfv[j];
    else { nim = nimv[j]; ljm = ljmv[j]; }
    f32x16 acc;
    #pragma unroll
    for (int q = 0; q < 16; ++q) acc[q] = 0.f;
    #pragma unroll
    for (int kc = 0; kc < KC; ++kc)
      acc = __builtin_amdgcn_mfma_f32_32x32x16_bf16(a[kc], bv[kc * 64 + lane], acc, 0, 0, 0);
    #pragma unroll
    for (int r = 0; r < 16; ++r) {
      if (MODE == 0) {
        float e = __expf(acc[r] * INV_TAU);
        Ssum[r] += e;
        Psum[r] = fmaf(pf, e, Psum[r]);
      } else {
        float t = acc[r] * INV_TAU;
        float e = __expf(t);
        Ssum[r] = fmaf(nim, e, Ssum[r]);
        Psum[r] += (limf[r] == ljm) ? t : 0.f;
      }
    }
    __syncthreads();
  }
  // reduce across the 32 lanes sharing each row, then one atomic per row
  #pragma unroll
  for (int r = 0; r < 16; ++r) {
    float s = Ssum[r], p = Psum[r];
    #pragma unroll
    for (int m = 1; m < 32; m <<= 1) { s += __shfl_xor(s, m); p += __shfl_xor(p, m); }
    if ((lane & 31) == 0) {
      int row = (r & 3) + 8 * (r >> 2) + 4 * (lane >> 5);
      atomicAdd(&Sg[itile * 32 + row], s);
      atomicAdd(&Pg[itile * 32 + row], p);
    }
  }
}

// ---------------- per-row losses + weighted reduction ----------------
__global__ __launch_bounds__(256) void finalize_kernel(
    const float* __restrict__ Sfg, const float* __restrict__ Pfg,
    const float* __restrict__ Scls, const float* __restrict__ SPc,
    const float* __restrict__ tiif, const float* __restrict__ tiic,
    const int* __restrict__ labels, const float* __restrict__ ious,
    const int* __restrict__ cnt, float* __restrict__ accum) {
  int i = blockIdx.x * 256 + threadIdx.x;
  int l = labels[i];
  float iv = ious[i];
  float w = (iv > 0.5f) ? iv : 0.f;
  int cntP = 0;
  #pragma unroll
  for (int b = 2; b <= 21; ++b) cntP += cnt[b];
  int cntNI = N_ROI - cnt[0];
  bool Pi = (l > 0);
  float numF = 0.f, denF = 0.f, numC = 0.f, denC = 0.f;
  // fg: subtract diagonal term e^{5*(z.z)_bf16}
  float eF = __expf(INV_TAU * tiif[i]);
  float Sf = Sfg[i] - eF;
  float Pf = Pfg[i] - (Pi ? eF : 0.f);
  int nposF = cntP - (Pi ? 1 : 0);
  if (Pi && nposF > 0) {
    float lossF = logf((Sf + 1e-8f) / (Pf + 1e-8f));
    numF = lossF * w; denF = w;
  }
  // cls
  float tC = INV_TAU * tiic[i];
  float eC = __expf(tC);
  float Sc = Scls[i] - ((l != -1) ? eC : 0.f);
  float SP = SPc[i] - (Pi ? tC : 0.f);
  int nposC = Pi ? (cnt[l + 1] - 1) : 0;
  bool anyv = (cntNI - ((l != -1) ? 1 : 0)) > 0;
  if (Pi && nposC > 0 && anyv) {
    float lse = logf(Sc);
    float lossC = -(SP - (float)nposC * lse) / fmaxf((float)nposC, 1.f);
    numC = lossC * w; denC = w;
  }
  float v0 = numF, v1 = denF, v2 = numC, v3 = denC;
  #pragma unroll
  for (int m = 1; m < 64; m <<= 1) {
    v0 += __shfl_xor(v0, m); v1 += __shfl_xor(v1, m);
    v2 += __shfl_xor(v2, m); v3 += __shfl_xor(v3, m);
  }
  __shared__ float red[4][4];
  int lane = threadIdx.x & 63, wid = threadIdx.x >> 6;
  if (lane == 0) { red[wid][0]=v0; red[wid][1]=v1; red[wid][2]=v2; red[wid][3]=v3; }
  __syncthreads();
  if (threadIdx.x == 0) {
    float s0=0,s1=0,s2=0,s3=0;
    for (int wvq = 0; wvq < 4; ++wvq) { s0+=red[wvq][0]; s1+=red[wvq][1]; s2+=red[wvq][2]; s3+=red[wvq][3]; }
    atomicAdd(&accum[0], s0); atomicAdd(&accum[1], s1);
    atomicAdd(&accum[2], s2); atomicAdd(&accum[3], s3);
  }
}

__global__ void write_out_kernel(const float* __restrict__ accum, float* __restrict__ out) {
  out[0] = accum[0] / (accum[1] + 1e-8f);
  out[1] = accum[2] / (accum[3] + 1e-12f);
}

extern "C" void kernel_launch(void* const* d_in, const int* in_sizes, int n_in,
                              void* d_out, int out_size, void* d_ws, size_t ws_size,
                              hipStream_t stream) {
  const float* X    = (const float*)d_in[0];
  const int*  labels= (const int*)d_in[1];
  const float* ious = (const float*)d_in[2];
  const float* w1f  = (const float*)d_in[3];
  const float* b1f  = (const float*)d_in[4];
  const float* w2f  = (const float*)d_in[5];
  const float* b2f  = (const float*)d_in[6];
  const float* w1c  = (const float*)d_in[7];
  const float* b1c  = (const float*)d_in[8];
  const float* w2c  = (const float*)d_in[9];
  const float* b2c  = (const float*)d_in[10];
  float* out = (float*)d_out;

  float* ws   = (float*)d_ws;
  float* H    = ws;                                // 8192*256 f32 (8 MB)
  float* Zf   = H  + (size_t)N_ROI * HIDD;         // 8192*64 f32
  float* Zc   = Zf + (size_t)N_ROI * FGD;          // 8192*128 f32
  float* Sfg  = Zc + (size_t)N_ROI * CLSD;
  float* Pfg  = Sfg + N_ROI;
  float* Scls = Pfg + N_ROI;
  float* SPc  = Scls + N_ROI;
  float* tiif = SPc + N_ROI;
  float* tiic = tiif + N_ROI;
  float* pfv  = tiic + N_ROI;
  float* nimv = pfv + N_ROI;
  float* ljmv = nimv + N_ROI;
  float* accum= ljmv + N_ROI;                      // 8 floats
  int*   cnt  = (int*)(accum + 8);                 // 24 ints
  // bf16 frag-packed copies live in H's region (H is dead after gemm2 of cls head)
  short* Zrf  = (short*)H;                         // 8192*64  bf16 (1 MB)
  short* Zrc  = (short*)(H + 262144);              // 8192*128 bf16 (2 MB)

  prep_zero_kernel<<<1, 64, 0, stream>>>(accum, cnt);
  prep_stats_kernel<<<N_ROI/256, 256, 0, stream>>>(labels, Sfg, Pfg, Scls, SPc,
                                                   pfv, nimv, ljmv, cnt);

  // both MLP chains first (H reused), then normalize+pack (frees H for Zr*)
  gemm_nt_kernel<<<dim3(N_ROI/64, HIDD/64), 256, 0, stream>>>(X, w1f, b1f, H, N_ROI, HIDD, C_IN, 1);
  gemm_nt_kernel<<<dim3(N_ROI/64, FGD/64),  256, 0, stream>>>(H, w2f, b2f, Zf, N_ROI, FGD, HIDD, 0);
  gemm_nt_kernel<<<dim3(N_ROI/64, HIDD/64), 256, 0, stream>>>(X, w1c, b1c, H, N_ROI, HIDD, C_IN, 1);
  gemm_nt_kernel<<<dim3(N_ROI/64, CLSD/64), 256, 0, stream>>>(H, w2c, b2c, Zc, N_ROI, CLSD, HIDD, 0);
  normalize_pack_kernel<<<N_ROI, FGD,  0, stream>>>(Zf, Zrf, tiif, FGD);
  normalize_pack_kernel<<<N_ROI, CLSD, 0, stream>>>(Zc, Zrc, tiic, CLSD);

  // MFMA Gram losses: grid (64 i-blocks x 16 j-chunks), 4 waves = 4 i-tiles/block
  loss_mfma_kernel<FGD, 0, 16><<<dim3(64, 16), 256, 0, stream>>>(Zrf, labels, pfv, nimv, ljmv, Sfg, Pfg);
  loss_mfma_kernel<CLSD, 1, 16><<<dim3(64, 16), 256, 0, stream>>>(Zrc, labels, pfv, nimv, ljmv, Scls, SPc);

  finalize_kernel<<<N_ROI/256, 256, 0, stream>>>(Sfg, Pfg, Scls, SPc, tiif, tiic,
                                                 labels, ious, cnt, accum);
  write_out_kernel<<<1, 1, 0, stream>>>(accum, out);
}

// Round 3
// 229.644 us; speedup vs baseline: 2.9891x; 1.5193x over previous
//
#include <hip/hip_runtime.h>
#include <hip/hip_bf16.h>
#include <math.h>

#define N_ROI 8192
#define C_IN  1024
#define HIDD  256
#define FGD   64
#define CLSD  128
#define INV_TAU 5.0f

using frag_ab = __attribute__((ext_vector_type(8))) short;   // 8 bf16 = 4 VGPRs
using f32x16  = __attribute__((ext_vector_type(16))) float;

static __device__ __forceinline__ short f32_to_bf16_bits(float f) {
  unsigned u = __builtin_bit_cast(unsigned, f);
  u = (u + 0x7FFFu + ((u >> 16) & 1u)) >> 16;   // RNE (inputs finite)
  return (short)u;
}
static __device__ __forceinline__ float bf16_bits_to_f32(short b) {
  unsigned u = ((unsigned)(unsigned short)b) << 16;
  return __builtin_bit_cast(float, u);
}

// ---------------- prep ----------------
__global__ void prep_zero_kernel(float* accum, int* cnt) {
  int t = threadIdx.x;
  if (t < 8) accum[t] = 0.f;
  if (t < 24) cnt[t] = 0;
}

__global__ void prep_stats_kernel(const int* __restrict__ labels,
                                  float* __restrict__ Sfg, float* __restrict__ Pfg,
                                  float* __restrict__ Scls, float* __restrict__ SPc,
                                  float* __restrict__ pfv, float* __restrict__ nimv,
                                  float* __restrict__ ljmv, int* __restrict__ cnt) {
  int i = blockIdx.x * blockDim.x + threadIdx.x;
  if (i >= N_ROI) return;
  Sfg[i] = 0.f; Pfg[i] = 0.f; Scls[i] = 0.f; SPc[i] = 0.f;
  int l = labels[i];
  pfv[i]  = (l > 0)  ? 1.f : 0.f;
  nimv[i] = (l != -1) ? 1.f : 0.f;
  ljmv[i] = (l > 0)  ? (float)l : -7.f;
  int b = l + 1; if (b < 0) b = 0; if (b > 21) b = 21;
  atomicAdd(&cnt[b], 1);
}

// ---------------- pack weights fp32 -> bf16 frag order ----------------
// frag layout: [tile=r/32][kc=c/16][lane=((c>>3)&1)*32 + (r&31)][8]
__global__ __launch_bounds__(256) void pack_w_kernel(
    const float* __restrict__ w1f, const float* __restrict__ w1c,
    const float* __restrict__ w2f, const float* __restrict__ w2c,
    short* __restrict__ W1pf, short* __restrict__ W1pc,
    short* __restrict__ W2pf, short* __restrict__ W2pc) {
  int b = blockIdx.x;
  const float* src; short* dst; int Ksh; int b0;
  if (b < 128)      { src = w1f; dst = W1pf; Ksh = 10; b0 = 0; }
  else if (b < 256) { src = w1c; dst = W1pc; Ksh = 10; b0 = 128; }
  else if (b < 264) { src = w2f; dst = W2pf; Ksh = 8;  b0 = 256; }
  else              { src = w2c; dst = W2pc; Ksh = 8;  b0 = 264; }
  int K = 1 << Ksh;
  int f = (b - b0) * 256 + threadIdx.x;
  int r = f >> (Ksh - 3);
  int c0 = (f & ((K >> 3) - 1)) << 3;
  float4 v0 = *(const float4*)(src + (size_t)r * K + c0);
  float4 v1 = *(const float4*)(src + (size_t)r * K + c0 + 4);
  union { short s[8]; uint4 v; } o;
  o.s[0] = f32_to_bf16_bits(v0.x); o.s[1] = f32_to_bf16_bits(v0.y);
  o.s[2] = f32_to_bf16_bits(v0.z); o.s[3] = f32_to_bf16_bits(v0.w);
  o.s[4] = f32_to_bf16_bits(v1.x); o.s[5] = f32_to_bf16_bits(v1.y);
  o.s[6] = f32_to_bf16_bits(v1.z); o.s[7] = f32_to_bf16_bits(v1.w);
  ((uint4*)dst)[(size_t)((r >> 5) * (K >> 4) + (c0 >> 4)) * 64 +
                ((c0 >> 3) & 1) * 32 + (r & 31)] = o.v;
}

// ---------------- GEMM1: Hp = relu(X @ W1^T + b1), bf16 MFMA, frag-packed out --------
// block 128M x 128N, 4 waves 2x2, wave 64x64 (2x2 acc of 32x32), BK=32 dbuf
__global__ __launch_bounds__(256) void gemm1_kernel(
    const float* __restrict__ X,
    const short* __restrict__ W1pf, const short* __restrict__ W1pc,
    const float* __restrict__ b1f, const float* __restrict__ b1c,
    short* __restrict__ Hpf, short* __restrict__ Hpc) {
  __shared__ union {
    uint4 stage[2][1024];      // [buf][A 0..511 | B 512..1023]
    short tr[4][64][68];       // epilogue transpose, 34816 B
  } sm;
  int tid = threadIdx.x, lane = tid & 63, wv = tid >> 6;
  int Mb = blockIdx.x, Nb = blockIdx.y;
  const short* W1p = blockIdx.z ? W1pc : W1pf;
  const float* b1  = blockIdx.z ? b1c  : b1f;
  short*       Hp  = blockIdx.z ? Hpc  : Hpf;
  int wm = wv >> 1, wn = wv & 1;
  const uint4* W1v = (const uint4*)W1p;

  float4 av[2][2];
  uint4  bv[2];

  auto loadAB = [&](int c) {
    #pragma unroll
    for (int q = 0; q < 2; ++q) {
      int u = q * 256 + tid;
      int row = Mb * 128 + ((u >> 7) << 5) + (u & 31);
      int col = c * 32 + ((u >> 5) & 3) * 8;
      const float* p = X + (size_t)row * C_IN + col;
      av[q][0] = *(const float4*)p;
      av[q][1] = *(const float4*)(p + 4);
      int nt = u >> 7, rem = u & 127;
      bv[q] = W1v[(size_t)((Nb * 4 + nt) * 64 + c * 2) * 64 + rem];
    }
  };
  auto storeStage = [&](int buf) {
    #pragma unroll
    for (int q = 0; q < 2; ++q) {
      int u = q * 256 + tid;
      union { short s[8]; uint4 v; } o;
      o.s[0] = f32_to_bf16_bits(av[q][0].x); o.s[1] = f32_to_bf16_bits(av[q][0].y);
      o.s[2] = f32_to_bf16_bits(av[q][0].z); o.s[3] = f32_to_bf16_bits(av[q][0].w);
      o.s[4] = f32_to_bf16_bits(av[q][1].x); o.s[5] = f32_to_bf16_bits(av[q][1].y);
      o.s[6] = f32_to_bf16_bits(av[q][1].z); o.s[7] = f32_to_bf16_bits(av[q][1].w);
      sm.stage[buf][u] = o.v;
      sm.stage[buf][512 + u] = bv[q];
    }
  };

  f32x16 acc[2][2];
  #pragma unroll
  for (int i = 0; i < 2; ++i)
    #pragma unroll
    for (int j = 0; j < 2; ++j)
      #pragma unroll
      for (int q = 0; q < 16; ++q) acc[i][j][q] = 0.f;

  loadAB(0);
  storeStage(0);
  for (int c = 0; c < 32; ++c) {
    __syncthreads();
    if (c + 1 < 32) loadAB(c + 1);
    int buf = c & 1;
    #pragma unroll
    for (int kc = 0; kc < 2; ++kc) {
      frag_ab a0 = *(const frag_ab*)&sm.stage[buf][(wm * 2 + 0) * 128 + kc * 64 + lane];
      frag_ab a1 = *(const frag_ab*)&sm.stage[buf][(wm * 2 + 1) * 128 + kc * 64 + lane];
      frag_ab b0 = *(const frag_ab*)&sm.stage[buf][512 + (wn * 2 + 0) * 128 + kc * 64 + lane];
      frag_ab b1_ = *(const frag_ab*)&sm.stage[buf][512 + (wn * 2 + 1) * 128 + kc * 64 + lane];
      acc[0][0] = __builtin_amdgcn_mfma_f32_32x32x16_bf16(a0, b0,  acc[0][0], 0, 0, 0);
      acc[0][1] = __builtin_amdgcn_mfma_f32_32x32x16_bf16(a0, b1_, acc[0][1], 0, 0, 0);
      acc[1][0] = __builtin_amdgcn_mfma_f32_32x32x16_bf16(a1, b0,  acc[1][0], 0, 0, 0);
      acc[1][1] = __builtin_amdgcn_mfma_f32_32x32x16_bf16(a1, b1_, acc[1][1], 0, 0, 0);
    }
    if (c + 1 < 32) storeStage((c + 1) & 1);
  }
  __syncthreads();   // all frag reads done before tr overwrite

  int cl_ = lane & 31, h = lane >> 5;
  #pragma unroll
  for (int i = 0; i < 2; ++i)
    #pragma unroll
    for (int j = 0; j < 2; ++j) {
      int cg = Nb * 128 + wn * 64 + j * 32 + cl_;
      float bb = b1[cg];
      #pragma unroll
      for (int g = 0; g < 4; ++g) {
        short4 s4;
        {
          float x0 = fmaxf(acc[i][j][g * 4 + 0] + bb, 0.f);
          float x1 = fmaxf(acc[i][j][g * 4 + 1] + bb, 0.f);
          float x2 = fmaxf(acc[i][j][g * 4 + 2] + bb, 0.f);
          float x3 = fmaxf(acc[i][j][g * 4 + 3] + bb, 0.f);
          s4 = make_short4(f32_to_bf16_bits(x0), f32_to_bf16_bits(x1),
                           f32_to_bf16_bits(x2), f32_to_bf16_bits(x3));
        }
        *(short4*)&sm.tr[wv][j * 32 + cl_][i * 32 + 4 * h + 8 * g] = s4;
      }
    }
  __syncthreads();
  uint4* Hv4 = (uint4*)Hp;
  #pragma unroll
  for (int k = 0; k < 8; ++k) {
    union { short s[8]; uint4 v; } o;
    #pragma unroll
    for (int e = 0; e < 8; ++e) o.s[e] = sm.tr[wv][k * 8 + e][lane];
    int rg = Mb * 128 + wm * 64 + lane;
    int cgk = Nb * 128 + wn * 64 + k * 8;
    Hv4[(size_t)((rg >> 5) * 16 + (cgk >> 4)) * 64 + ((cgk >> 3) & 1) * 32 + (rg & 31)] = o.v;
  }
}

// ---------------- GEMM2 + normalize + bf16 frag pack, fused ----------------
template<int D>
__device__ __forceinline__ void gemm2_head(
    const short* __restrict__ Hp, const short* __restrict__ W2p,
    const float* __restrict__ b2, short* __restrict__ Zr,
    float* __restrict__ tii, short* __restrict__ T, int mb) {
  int lane = threadIdx.x & 63;
  int wv = threadIdx.x >> 6;
  int gt = mb * 4 + wv;                       // 32-row tile
  const frag_ab* Hv = (const frag_ab*)Hp;
  const frag_ab* Wv = (const frag_ab*)W2p;
  constexpr int NT = D / 32;
  frag_ab a[16];
  #pragma unroll
  for (int kc = 0; kc < 16; ++kc) a[kc] = Hv[(size_t)(gt * 16 + kc) * 64 + lane];
  f32x16 acc[NT];
  #pragma unroll
  for (int j = 0; j < NT; ++j)
    #pragma unroll
    for (int q = 0; q < 16; ++q) acc[j][q] = 0.f;
  #pragma unroll
  for (int kc = 0; kc < 16; ++kc)
    #pragma unroll
    for (int j = 0; j < NT; ++j)
      acc[j] = __builtin_amdgcn_mfma_f32_32x32x16_bf16(a[kc], Wv[(j * 16 + kc) * 64 + lane], acc[j], 0, 0, 0);
  int c = lane & 31, h = lane >> 5;
  float bb[NT];
  #pragma unroll
  for (int j = 0; j < NT; ++j) bb[j] = b2[j * 32 + c];
  float s1[16];
  #pragma unroll
  for (int r = 0; r < 16; ++r) {
    s1[r] = 0.f;
    #pragma unroll
    for (int j = 0; j < NT; ++j) {
      float v = acc[j][r] + bb[j];
      s1[r] += v * v;
    }
  }
  #pragma unroll
  for (int r = 0; r < 16; ++r)
    #pragma unroll
    for (int m = 1; m < 32; m <<= 1) s1[r] += __shfl_xor(s1[r], m);
  float s2[16];
  #pragma unroll
  for (int r = 0; r < 16; ++r) s2[r] = 0.f;
  #pragma unroll
  for (int j = 0; j < NT; ++j) {
    int cl = j * 32 + c;
    #pragma unroll
    for (int g = 0; g < 4; ++g) {
      short q0, q1, q2, q3;
      #pragma unroll
      for (int e = 0; e < 4; ++e) {
        int r = g * 4 + e;
        float sc = 1.f / fmaxf(sqrtf(s1[r]), 1e-8f);
        short qb = f32_to_bf16_bits((acc[j][r] + bb[j]) * sc);
        float zf = bf16_bits_to_f32(qb);
        s2[r] += zf * zf;
        if (e == 0) q0 = qb; else if (e == 1) q1 = qb; else if (e == 2) q2 = qb; else q3 = qb;
      }
      *(short4*)&T[cl * 36 + 4 * h + 8 * g] = make_short4(q0, q1, q2, q3);
    }
  }
  #pragma unroll
  for (int r = 0; r < 16; ++r)
    #pragma unroll
    for (int m = 1; m < 32; m <<= 1) s2[r] += __shfl_xor(s2[r], m);
  if (c == 0) {
    #pragma unroll
    for (int r = 0; r < 16; ++r)
      tii[gt * 32 + (r & 3) + 8 * (r >> 2) + 4 * h] = s2[r];
  }
  __syncthreads();
  uint4* Zv = (uint4*)Zr;
  #pragma unroll
  for (int k = 0; k < D / 16; ++k) {
    int c0 = (2 * k + h) * 8;
    union { short s[8]; uint4 u; } o;
    #pragma unroll
    for (int e = 0; e < 8; ++e) o.s[e] = T[(c0 + e) * 36 + c];
    Zv[(size_t)(gt * (D / 16) + k) * 64 + h * 32 + c] = o.u;
  }
}

__global__ __launch_bounds__(256) void gemm2_kernel(
    const short* __restrict__ Hpf, const short* __restrict__ Hpc,
    const short* __restrict__ W2pf, const short* __restrict__ W2pc,
    const float* __restrict__ b2f, const float* __restrict__ b2c,
    short* __restrict__ Zrf, short* __restrict__ Zrc,
    float* __restrict__ tiif, float* __restrict__ tiic) {
  __shared__ short T2[4][128 * 36];
  int wv = threadIdx.x >> 6;
  if ((int)blockIdx.x < 64)
    gemm2_head<64>(Hpf, W2pf, b2f, Zrf, tiif, T2[wv], blockIdx.x);
  else
    gemm2_head<128>(Hpc, W2pc, b2c, Zrc, tiic, T2[wv], blockIdx.x - 64);
}

// ---------------- MFMA Gram-row-reduction loss kernel (unchanged from R2) ----------
template<int D, int MODE, int NJT>
__global__ __launch_bounds__(256) void loss_mfma_kernel(
    const short* __restrict__ Zr, const int* __restrict__ labels,
    const float* __restrict__ pfv, const float* __restrict__ nimv,
    const float* __restrict__ ljmv,
    float* __restrict__ Sg, float* __restrict__ Pg) {
  constexpr int KC = D / 16;
  __shared__ __align__(16) short sbuf[2][KC * 512];
  int tid = threadIdx.x, lane = tid & 63, wv = tid >> 6;
  int itile = blockIdx.x * 4 + wv;
  const frag_ab* Zrv = (const frag_ab*)Zr;
  frag_ab a[KC];
  #pragma unroll
  for (int kc = 0; kc < KC; ++kc) a[kc] = Zrv[(itile * KC + kc) * 64 + lane];
  float limf[16];
  if (MODE == 1) {
    #pragma unroll
    for (int r = 0; r < 16; ++r) {
      int row = (r & 3) + 8 * (r >> 2) + 4 * (lane >> 5);
      limf[r] = (float)labels[itile * 32 + row];
    }
  }
  float Ssum[16] = {}, Psum[16] = {};
  int jt0 = blockIdx.y * NJT;
  {
    const uint4* src = (const uint4*)(Zr + (size_t)jt0 * KC * 512);
    uint4* dst = (uint4*)sbuf[0];
    #pragma unroll
    for (int q = 0; q < KC * 64; q += 256) dst[q + tid] = src[q + tid];
  }
  __syncthreads();
  for (int kk = 0; kk < NJT; ++kk) {
    int jt = jt0 + kk;
    if (kk + 1 < NJT) {
      const uint4* src = (const uint4*)(Zr + (size_t)(jt + 1) * KC * 512);
      uint4* dst = (uint4*)sbuf[(kk + 1) & 1];
      #pragma unroll
      for (int q = 0; q < KC * 64; q += 256) dst[q + tid] = src[q + tid];
    }
    const frag_ab* bvf = (const frag_ab*)sbuf[kk & 1];
    int j = jt * 32 + (lane & 31);
    float pf = 0.f, nim = 0.f, ljm = 0.f;
    if (MODE == 0) pf = pfv[j];
    else { nim = nimv[j]; ljm = ljmv[j]; }
    f32x16 acc;
    #pragma unroll
    for (int q = 0; q < 16; ++q) acc[q] = 0.f;
    #pragma unroll
    for (int kc = 0; kc < KC; ++kc)
      acc = __builtin_amdgcn_mfma_f32_32x32x16_bf16(a[kc], bvf[kc * 64 + lane], acc, 0, 0, 0);
    #pragma unroll
    for (int r = 0; r < 16; ++r) {
      if (MODE == 0) {
        float e = __expf(acc[r] * INV_TAU);
        Ssum[r] += e;
        Psum[r] = fmaf(pf, e, Psum[r]);
      } else {
        float t = acc[r] * INV_TAU;
        float e = __expf(t);
        Ssum[r] = fmaf(nim, e, Ssum[r]);
        Psum[r] += (limf[r] == ljm) ? t : 0.f;
      }
    }
    __syncthreads();
  }
  #pragma unroll
  for (int r = 0; r < 16; ++r) {
    float s = Ssum[r], p = Psum[r];
    #pragma unroll
    for (int m = 1; m < 32; m <<= 1) { s += __shfl_xor(s, m); p += __shfl_xor(p, m); }
    if ((lane & 31) == 0) {
      int row = (r & 3) + 8 * (r >> 2) + 4 * (lane >> 5);
      atomicAdd(&Sg[itile * 32 + row], s);
      atomicAdd(&Pg[itile * 32 + row], p);
    }
  }
}

// ---------------- per-row losses + weighted reduction ----------------
__global__ __launch_bounds__(256) void finalize_kernel(
    const float* __restrict__ Sfg, const float* __restrict__ Pfg,
    const float* __restrict__ Scls, const float* __restrict__ SPc,
    const float* __restrict__ tiif, const float* __restrict__ tiic,
    const int* __restrict__ labels, const float* __restrict__ ious,
    const int* __restrict__ cnt, float* __restrict__ accum) {
  int i = blockIdx.x * 256 + threadIdx.x;
  int l = labels[i];
  float iv = ious[i];
  float w = (iv > 0.5f) ? iv : 0.f;
  int cntP = 0;
  #pragma unroll
  for (int b = 2; b <= 21; ++b) cntP += cnt[b];
  int cntNI = N_ROI - cnt[0];
  bool Pi = (l > 0);
  float numF = 0.f, denF = 0.f, numC = 0.f, denC = 0.f;
  float eF = __expf(INV_TAU * tiif[i]);
  float Sf = Sfg[i] - eF;
  float Pf = Pfg[i] - (Pi ? eF : 0.f);
  int nposF = cntP - (Pi ? 1 : 0);
  if (Pi && nposF > 0) {
    float lossF = logf((Sf + 1e-8f) / (Pf + 1e-8f));
    numF = lossF * w; denF = w;
  }
  float tC = INV_TAU * tiic[i];
  float eC = __expf(tC);
  float Sc = Scls[i] - ((l != -1) ? eC : 0.f);
  float SP = SPc[i] - (Pi ? tC : 0.f);
  int nposC = Pi ? (cnt[l + 1] - 1) : 0;
  bool anyv = (cntNI - ((l != -1) ? 1 : 0)) > 0;
  if (Pi && nposC > 0 && anyv) {
    float lse = logf(Sc);
    float lossC = -(SP - (float)nposC * lse) / fmaxf((float)nposC, 1.f);
    numC = lossC * w; denC = w;
  }
  float v0 = numF, v1 = denF, v2 = numC, v3 = denC;
  #pragma unroll
  for (int m = 1; m < 64; m <<= 1) {
    v0 += __shfl_xor(v0, m); v1 += __shfl_xor(v1, m);
    v2 += __shfl_xor(v2, m); v3 += __shfl_xor(v3, m);
  }
  __shared__ float red[4][4];
  int lane = threadIdx.x & 63, wid = threadIdx.x >> 6;
  if (lane == 0) { red[wid][0]=v0; red[wid][1]=v1; red[wid][2]=v2; red[wid][3]=v3; }
  __syncthreads();
  if (threadIdx.x == 0) {
    float s0=0,s1=0,s2=0,s3=0;
    for (int q = 0; q < 4; ++q) { s0+=red[q][0]; s1+=red[q][1]; s2+=red[q][2]; s3+=red[q][3]; }
    atomicAdd(&accum[0], s0); atomicAdd(&accum[1], s1);
    atomicAdd(&accum[2], s2); atomicAdd(&accum[3], s3);
  }
}

__global__ void write_out_kernel(const float* __restrict__ accum, float* __restrict__ out) {
  out[0] = accum[0] / (accum[1] + 1e-8f);
  out[1] = accum[2] / (accum[3] + 1e-12f);
}

extern "C" void kernel_launch(void* const* d_in, const int* in_sizes, int n_in,
                              void* d_out, int out_size, void* d_ws, size_t ws_size,
                              hipStream_t stream) {
  const float* X    = (const float*)d_in[0];
  const int*  labels= (const int*)d_in[1];
  const float* ious = (const float*)d_in[2];
  const float* w1f  = (const float*)d_in[3];
  const float* b1f  = (const float*)d_in[4];
  const float* w2f  = (const float*)d_in[5];
  const float* b2f  = (const float*)d_in[6];
  const float* w1c  = (const float*)d_in[7];
  const float* b1c  = (const float*)d_in[8];
  const float* w2c  = (const float*)d_in[9];
  const float* b2c  = (const float*)d_in[10];
  float* out = (float*)d_out;

  char* w = (char*)d_ws;
  short* W1pf = (short*)w;            w += 524288;
  short* W1pc = (short*)w;            w += 524288;
  short* W2pf = (short*)w;            w += 32768;
  short* W2pc = (short*)w;            w += 65536;
  short* Hpf  = (short*)w;            w += 4194304;
  short* Hpc  = (short*)w;            w += 4194304;
  short* Zrf  = (short*)w;            w += 1048576;
  short* Zrc  = (short*)w;            w += 2097152;
  float* Sfg  = (float*)w;            w += 32768;
  float* Pfg  = (float*)w;            w += 32768;
  float* Scls = (float*)w;            w += 32768;
  float* SPc  = (float*)w;            w += 32768;
  float* tiif = (float*)w;            w += 32768;
  float* tiic = (float*)w;            w += 32768;
  float* pfv  = (float*)w;            w += 32768;
  float* nimv = (float*)w;            w += 32768;
  float* ljmv = (float*)w;            w += 32768;
  float* accum= (float*)w;            w += 32;
  int*   cnt  = (int*)w;              w += 96;

  prep_zero_kernel<<<1, 64, 0, stream>>>(accum, cnt);
  prep_stats_kernel<<<N_ROI/256, 256, 0, stream>>>(labels, Sfg, Pfg, Scls, SPc,
                                                   pfv, nimv, ljmv, cnt);
  pack_w_kernel<<<280, 256, 0, stream>>>(w1f, w1c, w2f, w2c, W1pf, W1pc, W2pf, W2pc);

  gemm1_kernel<<<dim3(64, 2, 2), 256, 0, stream>>>(X, W1pf, W1pc, b1f, b1c, Hpf, Hpc);
  gemm2_kernel<<<128, 256, 0, stream>>>(Hpf, Hpc, W2pf, W2pc, b2f, b2c,
                                        Zrf, Zrc, tiif, tiic);

  loss_mfma_kernel<FGD, 0, 16><<<dim3(64, 16), 256, 0, stream>>>(Zrf, labels, pfv, nimv, ljmv, Sfg, Pfg);
  loss_mfma_kernel<CLSD, 1, 16><<<dim3(64, 16), 256, 0, stream>>>(Zrc, labels, pfv, nimv, ljmv, Scls, SPc);

  finalize_kernel<<<N_ROI/256, 256, 0, stream>>>(Sfg, Pfg, Scls, SPc, tiif, tiic,
                                                 labels, ious, cnt, accum);
  write_out_kernel<<<1, 1, 0, stream>>>(accum, out);
}

// Round 4
// 209.354 us; speedup vs baseline: 3.2788x; 1.0969x over previous
//
#include <hip/hip_runtime.h>
#include <hip/hip_bf16.h>
#include <math.h>

#define N_ROI 8192
#define C_IN  1024
#define HIDD  256
#define FGD   64
#define CLSD  128
#define INV_TAU 5.0f

using frag_ab = __attribute__((ext_vector_type(8))) short;   // 8 bf16 = 4 VGPRs
using f32x16  = __attribute__((ext_vector_type(16))) float;

static __device__ __forceinline__ short f32_to_bf16_bits(float f) {
  unsigned u = __builtin_bit_cast(unsigned, f);
  u = (u + 0x7FFFu + ((u >> 16) & 1u)) >> 16;   // RNE (inputs finite)
  return (short)u;
}
static __device__ __forceinline__ float bf16_bits_to_f32(short b) {
  unsigned u = ((unsigned)(unsigned short)b) << 16;
  return __builtin_bit_cast(float, u);
}

// ---------------- prep ----------------
__global__ void prep_zero_kernel(float* accum, int* cnt) {
  int t = threadIdx.x;
  if (t < 8) accum[t] = 0.f;
  if (t < 24) cnt[t] = 0;
}

__global__ void prep_stats_kernel(const int* __restrict__ labels,
                                  float* __restrict__ Sfg, float* __restrict__ Pfg,
                                  float* __restrict__ Scls, float* __restrict__ SPc,
                                  float* __restrict__ pfv, float* __restrict__ nimv,
                                  float* __restrict__ ljmv, int* __restrict__ cnt) {
  int i = blockIdx.x * blockDim.x + threadIdx.x;
  if (i >= N_ROI) return;
  Sfg[i] = 0.f; Pfg[i] = 0.f; Scls[i] = 0.f; SPc[i] = 0.f;
  int l = labels[i];
  pfv[i]  = (l > 0)  ? 1.f : 0.f;
  nimv[i] = (l != -1) ? 1.f : 0.f;
  ljmv[i] = (l > 0)  ? (float)l : -7.f;
  int b = l + 1; if (b < 0) b = 0; if (b > 21) b = 21;
  atomicAdd(&cnt[b], 1);
}

// ---------------- pack weights fp32 -> bf16 frag order ----------------
// frag layout: uint4 idx = ((r>>5)*(K>>4) + (c0>>4))*64 + ((c0>>3)&1)*32 + (r&31)
__global__ __launch_bounds__(256) void pack_w_kernel(
    const float* __restrict__ w1f, const float* __restrict__ w1c,
    const float* __restrict__ w2f, const float* __restrict__ w2c,
    short* __restrict__ W1pf, short* __restrict__ W1pc,
    short* __restrict__ W2pf, short* __restrict__ W2pc) {
  int b = blockIdx.x;
  const float* src; short* dst; int Ksh; int b0;
  if (b < 128)      { src = w1f; dst = W1pf; Ksh = 10; b0 = 0; }
  else if (b < 256) { src = w1c; dst = W1pc; Ksh = 10; b0 = 128; }
  else if (b < 264) { src = w2f; dst = W2pf; Ksh = 8;  b0 = 256; }
  else              { src = w2c; dst = W2pc; Ksh = 8;  b0 = 264; }
  int K = 1 << Ksh;
  int f = (b - b0) * 256 + threadIdx.x;
  int r = f >> (Ksh - 3);
  int c0 = (f & ((K >> 3) - 1)) << 3;
  float4 v0 = *(const float4*)(src + (size_t)r * K + c0);
  float4 v1 = *(const float4*)(src + (size_t)r * K + c0 + 4);
  union { short s[8]; uint4 v; } o;
  o.s[0] = f32_to_bf16_bits(v0.x); o.s[1] = f32_to_bf16_bits(v0.y);
  o.s[2] = f32_to_bf16_bits(v0.z); o.s[3] = f32_to_bf16_bits(v0.w);
  o.s[4] = f32_to_bf16_bits(v1.x); o.s[5] = f32_to_bf16_bits(v1.y);
  o.s[6] = f32_to_bf16_bits(v1.z); o.s[7] = f32_to_bf16_bits(v1.w);
  ((uint4*)dst)[(size_t)((r >> 5) * (K >> 4) + (c0 >> 4)) * 64 +
                ((c0 >> 3) & 1) * 32 + (r & 31)] = o.v;
}

// ---------------- GEMM1: 32 rows x 512 cols (fg|cls fused), 256 blocks ----------
// 4 waves: wave wv owns cols [wv*128, wv*128+128); head = wv>>1.
// K chunks of 32, A staged fp32->bf16 in 2KB dbuf LDS, B streamed from L2.
__global__ __launch_bounds__(256) void gemm1_kernel(
    const float* __restrict__ X,
    const short* __restrict__ W1pf, const short* __restrict__ W1pc,
    const float* __restrict__ b1f, const float* __restrict__ b1c,
    short* __restrict__ Hpf, short* __restrict__ Hpc) {
  __shared__ union {
    short stageA[2][1024];        // [buf][(kci*64+lane)*8 + e]   4 KB
    short T[4][128 * 36];         // epilogue transpose, 36 KB
  } sm;
  int tid = threadIdx.x, lane = tid & 63, wv = tid >> 6;
  int Mb = blockIdx.x;                        // 32-row tile, 0..255
  const short* Wp = (wv >> 1) ? W1pc : W1pf;
  const float* b1 = (wv >> 1) ? b1c  : b1f;
  short*       Hp = (wv >> 1) ? Hpc  : Hpf;
  const uint4* Wv4 = (const uint4*)Wp;
  int arow = tid >> 3;            // 0..31
  int ac4  = tid & 7;             // 0..7 (float4 within 32-col chunk)
  const float* Xp = X + (size_t)(Mb * 32 + arow) * C_IN + ac4 * 4;
  int aslot = ((ac4 >> 2) * 64 + ((ac4 >> 1) & 1) * 32 + arow) * 8 + (ac4 & 1) * 4;

  float4 av;
  frag_ab breg[2][8];             // [bank][kci*4+nt]
  f32x16 acc[4];
  #pragma unroll
  for (int nt = 0; nt < 4; ++nt)
    #pragma unroll
    for (int q = 0; q < 16; ++q) acc[nt][q] = 0.f;

  auto loadA = [&](int c) { av = *(const float4*)(Xp + c * 32); };
  auto loadB = [&](int c, int s) {
    #pragma unroll
    for (int kci = 0; kci < 2; ++kci)
      #pragma unroll
      for (int nt = 0; nt < 4; ++nt)
        breg[s][kci * 4 + nt] =
            *(const frag_ab*)&Wv4[(size_t)(((wv & 1) * 4 + nt) * 64 + c * 2 + kci) * 64 + lane];
  };
  auto storeA = [&](int buf) {
    *(short4*)&sm.stageA[buf][aslot] =
        make_short4(f32_to_bf16_bits(av.x), f32_to_bf16_bits(av.y),
                    f32_to_bf16_bits(av.z), f32_to_bf16_bits(av.w));
  };
  auto domfma = [&](int buf, int bank) {
    frag_ab a0 = *(const frag_ab*)&sm.stageA[buf][(0 * 64 + lane) * 8];
    frag_ab a1 = *(const frag_ab*)&sm.stageA[buf][(1 * 64 + lane) * 8];
    #pragma unroll
    for (int nt = 0; nt < 4; ++nt)
      acc[nt] = __builtin_amdgcn_mfma_f32_32x32x16_bf16(a0, breg[bank][nt], acc[nt], 0, 0, 0);
    #pragma unroll
    for (int nt = 0; nt < 4; ++nt)
      acc[nt] = __builtin_amdgcn_mfma_f32_32x32x16_bf16(a1, breg[bank][4 + nt], acc[nt], 0, 0, 0);
  };

  loadA(0); loadB(0, 0); storeA(0);
  __syncthreads();
  for (int c = 0; c < 32; c += 2) {
    if (c + 1 < 32) { loadA(c + 1); loadB(c + 1, 1); }
    domfma(0, 0);
    if (c + 1 < 32) storeA(1);
    __syncthreads();
    if (c + 2 < 32) { loadA(c + 2); loadB(c + 2, 0); }
    domfma(1, 1);
    if (c + 2 < 32) storeA(0);
    __syncthreads();
  }
  // epilogue: relu+bias, quantize, transpose via per-wave LDS, write frag-packed H
  int cl31 = lane & 31, h = lane >> 5;
  short* T = sm.T[wv];
  #pragma unroll
  for (int nt = 0; nt < 4; ++nt) {
    int colLocal = nt * 32 + cl31;
    float bb = b1[(wv & 1) * 128 + colLocal];
    #pragma unroll
    for (int g = 0; g < 4; ++g) {
      float x0 = fmaxf(acc[nt][g * 4 + 0] + bb, 0.f);
      float x1 = fmaxf(acc[nt][g * 4 + 1] + bb, 0.f);
      float x2 = fmaxf(acc[nt][g * 4 + 2] + bb, 0.f);
      float x3 = fmaxf(acc[nt][g * 4 + 3] + bb, 0.f);
      *(short4*)&T[colLocal * 36 + 4 * h + 8 * g] =
          make_short4(f32_to_bf16_bits(x0), f32_to_bf16_bits(x1),
                      f32_to_bf16_bits(x2), f32_to_bf16_bits(x3));
    }
  }
  __syncthreads();
  uint4* Hv4 = (uint4*)Hp;
  #pragma unroll
  for (int k = 0; k < 8; ++k) {
    union { short s[8]; uint4 v; } o;
    int c0 = k * 16 + h * 8;
    #pragma unroll
    for (int e = 0; e < 8; ++e) o.s[e] = T[(c0 + e) * 36 + cl31];
    Hv4[(size_t)(Mb * 16 + (wv & 1) * 8 + k) * 64 + h * 32 + cl31] = o.v;
  }
}

// ---------------- GEMM2 + normalize + bf16 frag pack, fused (1 wave = 1 tile) ------
template<int D>
__device__ __forceinline__ void gemm2_head(
    const short* __restrict__ Hp, const short* __restrict__ W2p,
    const float* __restrict__ b2, short* __restrict__ Zr,
    float* __restrict__ tii, short* __restrict__ T, int gt) {
  int lane = threadIdx.x & 63;
  const frag_ab* Hv = (const frag_ab*)Hp;
  const frag_ab* Wv = (const frag_ab*)W2p;
  constexpr int NT = D / 32;
  frag_ab a[16];
  #pragma unroll
  for (int kc = 0; kc < 16; ++kc) a[kc] = Hv[(size_t)(gt * 16 + kc) * 64 + lane];
  f32x16 acc[NT];
  #pragma unroll
  for (int j = 0; j < NT; ++j)
    #pragma unroll
    for (int q = 0; q < 16; ++q) acc[j][q] = 0.f;
  #pragma unroll
  for (int kc = 0; kc < 16; ++kc)
    #pragma unroll
    for (int j = 0; j < NT; ++j)
      acc[j] = __builtin_amdgcn_mfma_f32_32x32x16_bf16(a[kc], Wv[(j * 16 + kc) * 64 + lane], acc[j], 0, 0, 0);
  int c = lane & 31, h = lane >> 5;
  float bb[NT];
  #pragma unroll
  for (int j = 0; j < NT; ++j) bb[j] = b2[j * 32 + c];
  float s1[16];
  #pragma unroll
  for (int r = 0; r < 16; ++r) {
    s1[r] = 0.f;
    #pragma unroll
    for (int j = 0; j < NT; ++j) {
      float v = acc[j][r] + bb[j];
      s1[r] += v * v;
    }
  }
  #pragma unroll
  for (int r = 0; r < 16; ++r)
    #pragma unroll
    for (int m = 1; m < 32; m <<= 1) s1[r] += __shfl_xor(s1[r], m);
  float s2[16];
  #pragma unroll
  for (int r = 0; r < 16; ++r) s2[r] = 0.f;
  #pragma unroll
  for (int j = 0; j < NT; ++j) {
    int cl = j * 32 + c;
    #pragma unroll
    for (int g = 0; g < 4; ++g) {
      short q0, q1, q2, q3;
      #pragma unroll
      for (int e = 0; e < 4; ++e) {
        int r = g * 4 + e;
        float sc = 1.f / fmaxf(sqrtf(s1[r]), 1e-8f);
        short qb = f32_to_bf16_bits((acc[j][r] + bb[j]) * sc);
        float zf = bf16_bits_to_f32(qb);
        s2[r] += zf * zf;
        if (e == 0) q0 = qb; else if (e == 1) q1 = qb; else if (e == 2) q2 = qb; else q3 = qb;
      }
      *(short4*)&T[cl * 36 + 4 * h + 8 * g] = make_short4(q0, q1, q2, q3);
    }
  }
  #pragma unroll
  for (int r = 0; r < 16; ++r)
    #pragma unroll
    for (int m = 1; m < 32; m <<= 1) s2[r] += __shfl_xor(s2[r], m);
  if (c == 0) {
    #pragma unroll
    for (int r = 0; r < 16; ++r)
      tii[gt * 32 + (r & 3) + 8 * (r >> 2) + 4 * h] = s2[r];
  }
  __syncthreads();
  uint4* Zv = (uint4*)Zr;
  #pragma unroll
  for (int k = 0; k < D / 16; ++k) {
    int c0 = (2 * k + h) * 8;
    union { short s[8]; uint4 u; } o;
    #pragma unroll
    for (int e = 0; e < 8; ++e) o.s[e] = T[(c0 + e) * 36 + c];
    Zv[(size_t)(gt * (D / 16) + k) * 64 + h * 32 + c] = o.u;
  }
}

__global__ __launch_bounds__(128) void gemm2_kernel(
    const short* __restrict__ Hpf, const short* __restrict__ Hpc,
    const short* __restrict__ W2pf, const short* __restrict__ W2pc,
    const float* __restrict__ b2f, const float* __restrict__ b2c,
    short* __restrict__ Zrf, short* __restrict__ Zrc,
    float* __restrict__ tiif, float* __restrict__ tiic) {
  __shared__ short T2[2][128 * 36];
  int wv = threadIdx.x >> 6;
  int b = blockIdx.x;
  if (b < 128)
    gemm2_head<64>(Hpf, W2pf, b2f, Zrf, tiif, T2[wv], b * 2 + wv);
  else
    gemm2_head<128>(Hpc, W2pc, b2c, Zrc, tiic, T2[wv], (b - 128) * 2 + wv);
}

// ---------------- MFMA Gram-row-reduction loss (fg & cls in one launch) ----------
template<int D, int MODE, int NJT>
__device__ __forceinline__ void loss_body(
    short* sbuf, const short* __restrict__ Zr, const int* __restrict__ labels,
    const float* __restrict__ pfv, const float* __restrict__ nimv,
    const float* __restrict__ ljmv,
    float* __restrict__ Sg, float* __restrict__ Pg) {
  constexpr int KC = D / 16;
  int tid = threadIdx.x, lane = tid & 63, wv = tid >> 6;
  int itile = blockIdx.x * 4 + wv;
  const frag_ab* Zrv = (const frag_ab*)Zr;
  frag_ab a[KC];
  #pragma unroll
  for (int kc = 0; kc < KC; ++kc) a[kc] = Zrv[(itile * KC + kc) * 64 + lane];
  float limf[16];
  if (MODE == 1) {
    #pragma unroll
    for (int r = 0; r < 16; ++r) {
      int row = (r & 3) + 8 * (r >> 2) + 4 * (lane >> 5);
      limf[r] = (float)labels[itile * 32 + row];
    }
  }
  float Ssum[16] = {}, Psum[16] = {};
  int jt0 = blockIdx.y * NJT;
  {
    const uint4* src = (const uint4*)(Zr + (size_t)jt0 * KC * 512);
    uint4* dst = (uint4*)sbuf;
    #pragma unroll
    for (int q = 0; q < KC * 64; q += 256) dst[q + tid] = src[q + tid];
  }
  __syncthreads();
  for (int kk = 0; kk < NJT; ++kk) {
    int jt = jt0 + kk;
    if (kk + 1 < NJT) {
      const uint4* src = (const uint4*)(Zr + (size_t)(jt + 1) * KC * 512);
      uint4* dst = (uint4*)(sbuf + ((kk + 1) & 1) * KC * 512);
      #pragma unroll
      for (int q = 0; q < KC * 64; q += 256) dst[q + tid] = src[q + tid];
    }
    const frag_ab* bvf = (const frag_ab*)(sbuf + (kk & 1) * KC * 512);
    int j = jt * 32 + (lane & 31);
    float pf = 0.f, nim = 0.f, ljm = 0.f;
    if (MODE == 0) pf = pfv[j];
    else { nim = nimv[j]; ljm = ljmv[j]; }
    f32x16 acc;
    #pragma unroll
    for (int q = 0; q < 16; ++q) acc[q] = 0.f;
    #pragma unroll
    for (int kc = 0; kc < KC; ++kc)
      acc = __builtin_amdgcn_mfma_f32_32x32x16_bf16(a[kc], bvf[kc * 64 + lane], acc, 0, 0, 0);
    #pragma unroll
    for (int r = 0; r < 16; ++r) {
      if (MODE == 0) {
        float e = __expf(acc[r] * INV_TAU);
        Ssum[r] += e;
        Psum[r] = fmaf(pf, e, Psum[r]);
      } else {
        float t = acc[r] * INV_TAU;
        float e = __expf(t);
        Ssum[r] = fmaf(nim, e, Ssum[r]);
        Psum[r] += (limf[r] == ljm) ? t : 0.f;
      }
    }
    __syncthreads();
  }
  #pragma unroll
  for (int r = 0; r < 16; ++r) {
    float s = Ssum[r], p = Psum[r];
    #pragma unroll
    for (int m = 1; m < 32; m <<= 1) { s += __shfl_xor(s, m); p += __shfl_xor(p, m); }
    if ((lane & 31) == 0) {
      int row = (r & 3) + 8 * (r >> 2) + 4 * (lane >> 5);
      atomicAdd(&Sg[itile * 32 + row], s);
      atomicAdd(&Pg[itile * 32 + row], p);
    }
  }
}

__global__ __launch_bounds__(256) void loss_kernel(
    const short* __restrict__ Zrf, const short* __restrict__ Zrc,
    const int* __restrict__ labels,
    const float* __restrict__ pfv, const float* __restrict__ nimv,
    const float* __restrict__ ljmv,
    float* __restrict__ Sfg, float* __restrict__ Pfg,
    float* __restrict__ Scls, float* __restrict__ SPc) {
  __shared__ __align__(16) short sbuf[2 * 8 * 512];   // 16 KB (cls); fg uses half
  if (blockIdx.z == 0)
    loss_body<FGD, 0, 16>(sbuf, Zrf, labels, pfv, nimv, ljmv, Sfg, Pfg);
  else
    loss_body<CLSD, 1, 16>(sbuf, Zrc, labels, pfv, nimv, ljmv, Scls, SPc);
}

// ---------------- per-row losses + weighted reduction + write-out ----------------
__global__ __launch_bounds__(256) void finalize_kernel(
    const float* __restrict__ Sfg, const float* __restrict__ Pfg,
    const float* __restrict__ Scls, const float* __restrict__ SPc,
    const float* __restrict__ tiif, const float* __restrict__ tiic,
    const int* __restrict__ labels, const float* __restrict__ ious,
    int* __restrict__ cnt, float* __restrict__ accum, float* __restrict__ out) {
  int i = blockIdx.x * 256 + threadIdx.x;
  int l = labels[i];
  float iv = ious[i];
  float w = (iv > 0.5f) ? iv : 0.f;
  int cntP = 0;
  #pragma unroll
  for (int b = 2; b <= 21; ++b) cntP += cnt[b];
  int cntNI = N_ROI - cnt[0];
  bool Pi = (l > 0);
  float numF = 0.f, denF = 0.f, numC = 0.f, denC = 0.f;
  float eF = __expf(INV_TAU * tiif[i]);
  float Sf = Sfg[i] - eF;
  float Pf = Pfg[i] - (Pi ? eF : 0.f);
  int nposF = cntP - (Pi ? 1 : 0);
  if (Pi && nposF > 0) {
    float lossF = logf((Sf + 1e-8f) / (Pf + 1e-8f));
    numF = lossF * w; denF = w;
  }
  float tC = INV_TAU * tiic[i];
  float eC = __expf(tC);
  float Sc = Scls[i] - ((l != -1) ? eC : 0.f);
  float SP = SPc[i] - (Pi ? tC : 0.f);
  int nposC = Pi ? (cnt[l + 1] - 1) : 0;
  bool anyv = (cntNI - ((l != -1) ? 1 : 0)) > 0;
  if (Pi && nposC > 0 && anyv) {
    float lse = logf(Sc);
    float lossC = -(SP - (float)nposC * lse) / fmaxf((float)nposC, 1.f);
    numC = lossC * w; denC = w;
  }
  float v0 = numF, v1 = denF, v2 = numC, v3 = denC;
  #pragma unroll
  for (int m = 1; m < 64; m <<= 1) {
    v0 += __shfl_xor(v0, m); v1 += __shfl_xor(v1, m);
    v2 += __shfl_xor(v2, m); v3 += __shfl_xor(v3, m);
  }
  __shared__ float red[4][4];
  int lane = threadIdx.x & 63, wid = threadIdx.x >> 6;
  if (lane == 0) { red[wid][0]=v0; red[wid][1]=v1; red[wid][2]=v2; red[wid][3]=v3; }
  __syncthreads();
  if (threadIdx.x == 0) {
    float s0=0,s1=0,s2=0,s3=0;
    for (int q = 0; q < 4; ++q) { s0+=red[q][0]; s1+=red[q][1]; s2+=red[q][2]; s3+=red[q][3]; }
    atomicAdd(&accum[0], s0); atomicAdd(&accum[1], s1);
    atomicAdd(&accum[2], s2); atomicAdd(&accum[3], s3);
    __threadfence();
    int t = atomicAdd(&cnt[22], 1);
    if (t == 31) {                       // last of 32 blocks: write output
      __threadfence();
      out[0] = accum[0] / (accum[1] + 1e-8f);
      out[1] = accum[2] / (accum[3] + 1e-12f);
    }
  }
}

extern "C" void kernel_launch(void* const* d_in, const int* in_sizes, int n_in,
                              void* d_out, int out_size, void* d_ws, size_t ws_size,
                              hipStream_t stream) {
  const float* X    = (const float*)d_in[0];
  const int*  labels= (const int*)d_in[1];
  const float* ious = (const float*)d_in[2];
  const float* w1f  = (const float*)d_in[3];
  const float* b1f  = (const float*)d_in[4];
  const float* w2f  = (const float*)d_in[5];
  const float* b2f  = (const float*)d_in[6];
  const float* w1c  = (const float*)d_in[7];
  const float* b1c  = (const float*)d_in[8];
  const float* w2c  = (const float*)d_in[9];
  const float* b2c  = (const float*)d_in[10];
  float* out = (float*)d_out;

  char* w = (char*)d_ws;
  short* W1pf = (short*)w;            w += 524288;
  short* W1pc = (short*)w;            w += 524288;
  short* W2pf = (short*)w;            w += 32768;
  short* W2pc = (short*)w;            w += 65536;
  short* Hpf  = (short*)w;            w += 4194304;
  short* Hpc  = (short*)w;            w += 4194304;
  short* Zrf  = (short*)w;            w += 1048576;
  short* Zrc  = (short*)w;            w += 2097152;
  float* Sfg  = (float*)w;            w += 32768;
  float* Pfg  = (float*)w;            w += 32768;
  float* Scls = (float*)w;            w += 32768;
  float* SPc  = (float*)w;            w += 32768;
  float* tiif = (float*)w;            w += 32768;
  float* tiic = (float*)w;            w += 32768;
  float* pfv  = (float*)w;            w += 32768;
  float* nimv = (float*)w;            w += 32768;
  float* ljmv = (float*)w;            w += 32768;
  float* accum= (float*)w;            w += 32;
  int*   cnt  = (int*)w;              w += 96;

  prep_zero_kernel<<<1, 64, 0, stream>>>(accum, cnt);
  prep_stats_kernel<<<N_ROI/256, 256, 0, stream>>>(labels, Sfg, Pfg, Scls, SPc,
                                                   pfv, nimv, ljmv, cnt);
  pack_w_kernel<<<280, 256, 0, stream>>>(w1f, w1c, w2f, w2c, W1pf, W1pc, W2pf, W2pc);

  gemm1_kernel<<<256, 256, 0, stream>>>(X, W1pf, W1pc, b1f, b1c, Hpf, Hpc);
  gemm2_kernel<<<256, 128, 0, stream>>>(Hpf, Hpc, W2pf, W2pc, b2f, b2c,
                                        Zrf, Zrc, tiif, tiic);

  loss_kernel<<<dim3(64, 16, 2), 256, 0, stream>>>(Zrf, Zrc, labels, pfv, nimv, ljmv,
                                                   Sfg, Pfg, Scls, SPc);

  finalize_kernel<<<N_ROI/256, 256, 0, stream>>>(Sfg, Pfg, Scls, SPc, tiif, tiic,
                                                 labels, ious, cnt, accum, out);
}